// Round 3
// baseline (1284.251 us; speedup 1.0000x reference)
//
#include <hip/hip_runtime.h>
#include <math.h>

#define NNODES 200000
#define NEDGES 3200000
#define NG     256
#define NB1    98      // ceil(200000/2048)
#define NSLAB  512

static __device__ __forceinline__ float relu_(float x) { return x > 0.f ? x : 0.f; }
static __device__ __forceinline__ float sigmoid_(float x) { return 1.f / (1.f + expf(-x)); }

// ---------------- node encoder ----------------
__global__ __launch_bounds__(256) void k_node_enc(
    const float* __restrict__ nodes,
    const float* __restrict__ Wn1, const float* __restrict__ bn1,
    const float* __restrict__ Wn2, const float* __restrict__ bn2,
    float* __restrict__ nbuf)
{
    int v = blockIdx.x * 256 + threadIdx.x;
    if (v >= NNODES) return;
    float acc1[32];
#pragma unroll
    for (int j = 0; j < 32; j++) acc1[j] = bn1[j];
    const float4* xp = (const float4*)(nodes + (size_t)v * 128);
#pragma unroll 1
    for (int k4 = 0; k4 < 32; k4++) {
        float4 x = xp[k4];
        const float* w = Wn1 + k4 * 4 * 32;
#pragma unroll
        for (int j = 0; j < 32; j++) acc1[j] = fmaf(x.x, w[j], acc1[j]);
#pragma unroll
        for (int j = 0; j < 32; j++) acc1[j] = fmaf(x.y, w[32 + j], acc1[j]);
#pragma unroll
        for (int j = 0; j < 32; j++) acc1[j] = fmaf(x.z, w[64 + j], acc1[j]);
#pragma unroll
        for (int j = 0; j < 32; j++) acc1[j] = fmaf(x.w, w[96 + j], acc1[j]);
    }
#pragma unroll
    for (int j = 0; j < 32; j++) acc1[j] = relu_(acc1[j]);
    float acc2[16];
#pragma unroll
    for (int j = 0; j < 16; j++) acc2[j] = bn2[j];
#pragma unroll 1
    for (int k = 0; k < 32; k++) {
        const float* w = Wn2 + k * 16;
        float x = acc1[k];
#pragma unroll
        for (int j = 0; j < 16; j++) acc2[j] = fmaf(x, w[j], acc2[j]);
    }
    float4* o4 = (float4*)(nbuf + (size_t)v * 16);
    o4[0] = make_float4(relu_(acc2[0]), relu_(acc2[1]), relu_(acc2[2]), relu_(acc2[3]));
    o4[1] = make_float4(relu_(acc2[4]), relu_(acc2[5]), relu_(acc2[6]), relu_(acc2[7]));
    o4[2] = make_float4(relu_(acc2[8]), relu_(acc2[9]), relu_(acc2[10]), relu_(acc2[11]));
    o4[3] = make_float4(relu_(acc2[12]), relu_(acc2[13]), relu_(acc2[14]), relu_(acc2[15]));
}

// ---------------- degree histogram over receivers ----------------
__global__ __launch_bounds__(256) void k_deg(const int* __restrict__ receivers, int* __restrict__ deg)
{
    for (int i = blockIdx.x * 256 + threadIdx.x; i < NEDGES; i += gridDim.x * 256)
        atomicAdd(&deg[receivers[i]], 1);
}

// ---------------- hierarchical exclusive scan of deg -> off, cursor ----------------
__global__ __launch_bounds__(256) void k_scan1(const int* __restrict__ deg, int* __restrict__ bsum)
{
    __shared__ int ts[256];
    int b = blockIdx.x, t = threadIdx.x;
    int base = b * 2048 + t * 8;
    int s = 0;
#pragma unroll
    for (int u = 0; u < 8; u++) { int idx = base + u; if (idx < NNODES) s += deg[idx]; }
    ts[t] = s; __syncthreads();
    for (int ofs = 128; ofs > 0; ofs >>= 1) {
        if (t < ofs) ts[t] += ts[t + ofs];
        __syncthreads();
    }
    if (t == 0) bsum[b] = ts[0];
}

__global__ void k_scan2(const int* __restrict__ bsum, int* __restrict__ bpre)
{
    if (threadIdx.x == 0) {
        int acc = 0;
        for (int i = 0; i < NB1; i++) { bpre[i] = acc; acc += bsum[i]; }
    }
}

__global__ __launch_bounds__(256) void k_scan3(const int* __restrict__ deg, const int* __restrict__ bpre,
                                               int* __restrict__ off, int* __restrict__ cursor)
{
    __shared__ int ts[256];
    int b = blockIdx.x, t = threadIdx.x;
    int base = b * 2048 + t * 8;
    int loc[8]; int s = 0;
#pragma unroll
    for (int u = 0; u < 8; u++) {
        int idx = base + u;
        int d = (idx < NNODES) ? deg[idx] : 0;
        loc[u] = d; s += d;
    }
    ts[t] = s; __syncthreads();
    for (int ofs = 1; ofs < 256; ofs <<= 1) {
        int v = (t >= ofs) ? ts[t - ofs] : 0;
        __syncthreads();
        ts[t] += v;
        __syncthreads();
    }
    int ex = ((t == 0) ? 0 : ts[t - 1]) + bpre[b];
#pragma unroll
    for (int u = 0; u < 8; u++) {
        int idx = base + u;
        if (idx < NNODES) { off[idx] = ex; cursor[idx] = ex; ex += loc[u]; }
    }
    if (b == 0 && t == 0) off[NNODES] = NEDGES;
}

// ---------------- permutation build: pairs[pos] = {edge_idx, sender}; + ecnt hist ----------------
__global__ __launch_bounds__(256) void k_perm(
    const int* __restrict__ receivers, const int* __restrict__ senders,
    const int* __restrict__ node_graph,
    int* __restrict__ cursor, int2* __restrict__ pairs, int* __restrict__ ecnt)
{
    __shared__ int hist[NG];
    for (int i = threadIdx.x; i < NG; i += 256) hist[i] = 0;
    __syncthreads();
    for (int i = blockIdx.x * 256 + threadIdx.x; i < NEDGES; i += gridDim.x * 256) {
        int r = receivers[i];
        int s = senders[i];
        int pos = atomicAdd(&cursor[r], 1);
        pairs[pos] = make_int2(i, s);
        atomicAdd(&hist[node_graph[s]], 1);
    }
    __syncthreads();
    for (int i = threadIdx.x; i < NG; i += 256)
        if (hist[i]) atomicAdd(&ecnt[i], hist[i]);
}

// ---------------- graph start offsets in (sorted) node array ----------------
__global__ __launch_bounds__(256) void k_goff(const int* __restrict__ ng, int* __restrict__ goff)
{
    int v = blockIdx.x * 256 + threadIdx.x;
    if (v >= NNODES) return;
    int a = ng[v];
    if (v == 0) { for (int g = 0; g <= a; g++) goff[g] = 0; }
    else { int b = ng[v - 1]; for (int g = b + 1; g <= a; g++) goff[g] = v; }
    if (v == NNODES - 1) { for (int g = a + 1; g <= NG; g++) goff[g] = NNODES; }
}

// ---------------- per-graph node sum via contiguous ranges ----------------
__global__ __launch_bounds__(256) void k_gsum_nodes(
    const float* __restrict__ nbuf, const int* __restrict__ goff, float* __restrict__ gsum_n)
{
    __shared__ float red[256 * 16];
    int g = blockIdx.x, t = threadIdx.x;
    int s = goff[g], eN = goff[g + 1];
    float acc[16];
#pragma unroll
    for (int j = 0; j < 16; j++) acc[j] = 0.f;
    for (int v = s + t; v < eN; v += 256) {
        const float4* p = (const float4*)(nbuf + (size_t)v * 16);
#pragma unroll
        for (int q = 0; q < 4; q++) {
            float4 x = p[q];
            acc[q * 4] += x.x; acc[q * 4 + 1] += x.y; acc[q * 4 + 2] += x.z; acc[q * 4 + 3] += x.w;
        }
    }
#pragma unroll
    for (int j = 0; j < 16; j++) red[t * 16 + j] = acc[j];
    __syncthreads();
    for (int ofs = 128; ofs > 0; ofs >>= 1) {
        if (t < ofs) {
#pragma unroll
            for (int j = 0; j < 16; j++) red[t * 16 + j] += red[(t + ofs) * 16 + j];
        }
        __syncthreads();
    }
    if (t < 16) gsum_n[g * 16 + t] = red[t];
}

// ---------------- g encoder ----------------
__global__ void k_g_enc(
    const float* __restrict__ gsum_n, const int* __restrict__ goff,
    const float* __restrict__ Wg2, const float* __restrict__ bg2,
    float* __restrict__ g)
{
    int gi = threadIdx.x;
    float c = 1.f / fmaxf((float)(goff[gi + 1] - goff[gi]), 1.f);
    float nm[16];
#pragma unroll
    for (int k = 0; k < 16; k++) nm[k] = gsum_n[gi * 16 + k] * c;
    float acc[4];
#pragma unroll
    for (int j = 0; j < 4; j++) acc[j] = bg2[j];
#pragma unroll
    for (int k = 0; k < 16; k++) {
        const float* w = Wg2 + k * 4;
#pragma unroll
        for (int j = 0; j < 4; j++) acc[j] = fmaf(nm[k], w[j], acc[j]);
    }
    *(float4*)(g + gi * 4) = make_float4(acc[0], acc[1], acc[2], acc[3]);
}

// ---------------- fused hop: [encoder] + edge update + inc mean + node update [+ readout] ----------------
// MODE 0: first hop (encode edges inline, write e)
// MODE 1: middle hop (read e, write e)
// MODE 2: last hop (read e, skip dead e write, fused node readout)
template <int MODE>
__global__ __launch_bounds__(256) void k_fused_hop(
    const float* __restrict__ edges, const int2* __restrict__ pairs,
    const int* __restrict__ off, const int* __restrict__ node_graph,
    float* __restrict__ e,
    const float* __restrict__ nin, float* __restrict__ nout,
    const float* __restrict__ g,
    const float* __restrict__ We1, const float* __restrict__ be1,
    const float* __restrict__ We2, const float* __restrict__ be2,
    const float* __restrict__ He_e, const float* __restrict__ He_s,
    const float* __restrict__ He_g, const float* __restrict__ He_b,
    const float* __restrict__ Hn_n, const float* __restrict__ Hn_in,
    const float* __restrict__ Hn_g, const float* __restrict__ Hn_b,
    float* __restrict__ slab_e,
    const float* __restrict__ Rn, const float* __restrict__ Rn_b,
    float* __restrict__ out)
{
    __shared__ float bins[NG * 8];
    for (int i = threadIdx.x; i < NG * 8; i += 256) bins[i] = 0.f;
    __syncthreads();
    for (int v = blockIdx.x * 256 + threadIdx.x; v < NNODES; v += gridDim.x * 256) {
        int o0 = off[v], o1 = off[v + 1];
        float iv[8];
#pragma unroll
        for (int j = 0; j < 8; j++) iv[j] = 0.f;
#pragma unroll 1
        for (int p = o0; p < o1; p++) {
            int2 pr = pairs[p];
            int s = pr.y;
            float ev[8];
            if constexpr (MODE == 0) {
                // inline edge encoder from raw features (64B aligned gather)
                float x[16];
                const float4* xp = (const float4*)(edges + (size_t)pr.x * 16);
#pragma unroll
                for (int q = 0; q < 4; q++) {
                    float4 t = xp[q];
                    x[q * 4] = t.x; x[q * 4 + 1] = t.y; x[q * 4 + 2] = t.z; x[q * 4 + 3] = t.w;
                }
                float h1[4];
#pragma unroll
                for (int j = 0; j < 4; j++) h1[j] = be1[j];
#pragma unroll
                for (int k = 0; k < 16; k++) {
                    const float* w = We1 + k * 4;
#pragma unroll
                    for (int j = 0; j < 4; j++) h1[j] = fmaf(x[k], w[j], h1[j]);
                }
#pragma unroll
                for (int j = 0; j < 4; j++) h1[j] = relu_(h1[j]);
#pragma unroll
                for (int j = 0; j < 8; j++) ev[j] = be2[j];
#pragma unroll
                for (int k = 0; k < 4; k++) {
                    const float* w = We2 + k * 8;
#pragma unroll
                    for (int j = 0; j < 8; j++) ev[j] = fmaf(h1[k], w[j], ev[j]);
                }
#pragma unroll
                for (int j = 0; j < 8; j++) ev[j] = relu_(ev[j]);
            } else {
                const float4* pe = (const float4*)(e + (size_t)p * 8);
                float4 a = pe[0], b = pe[1];
                ev[0] = a.x; ev[1] = a.y; ev[2] = a.z; ev[3] = a.w;
                ev[4] = b.x; ev[5] = b.y; ev[6] = b.z; ev[7] = b.w;
            }
            int gid = node_graph[s];
            float ns[16];
            {
                const float4* pn = (const float4*)(nin + (size_t)s * 16);
#pragma unroll
                for (int q = 0; q < 4; q++) {
                    float4 t = pn[q];
                    ns[q * 4] = t.x; ns[q * 4 + 1] = t.y; ns[q * 4 + 2] = t.z; ns[q * 4 + 3] = t.w;
                }
            }
            float gv[4];
            {
                float4 t = *(const float4*)(g + gid * 4);
                gv[0] = t.x; gv[1] = t.y; gv[2] = t.z; gv[3] = t.w;
            }
            float acc[8];
#pragma unroll
            for (int j = 0; j < 8; j++) acc[j] = He_b[j];
#pragma unroll
            for (int k = 0; k < 8; k++) {
                const float* w = He_e + k * 8;
#pragma unroll
                for (int j = 0; j < 8; j++) acc[j] = fmaf(ev[k], w[j], acc[j]);
            }
#pragma unroll
            for (int k = 0; k < 16; k++) {
                const float* w = He_s + k * 8;
#pragma unroll
                for (int j = 0; j < 8; j++) acc[j] = fmaf(ns[k], w[j], acc[j]);
            }
#pragma unroll
            for (int k = 0; k < 4; k++) {
                const float* w = He_g + k * 8;
#pragma unroll
                for (int j = 0; j < 8; j++) acc[j] = fmaf(gv[k], w[j], acc[j]);
            }
#pragma unroll
            for (int j = 0; j < 8; j++) acc[j] = relu_(acc[j]);
            if constexpr (MODE != 2) {
                float4* pe = (float4*)(e + (size_t)p * 8);
                pe[0] = make_float4(acc[0], acc[1], acc[2], acc[3]);
                pe[1] = make_float4(acc[4], acc[5], acc[6], acc[7]);
            }
#pragma unroll
            for (int j = 0; j < 8; j++) iv[j] += acc[j];
#pragma unroll
            for (int j = 0; j < 8; j++) atomicAdd(&bins[gid * 8 + j], acc[j]);
        }
        // ---- node update ----
        float sc = 1.f / fmaxf((float)(o1 - o0), 1.f);
#pragma unroll
        for (int j = 0; j < 8; j++) iv[j] *= sc;
        float nv[16];
        {
            const float4* pn = (const float4*)(nin + (size_t)v * 16);
#pragma unroll
            for (int q = 0; q < 4; q++) {
                float4 t = pn[q];
                nv[q * 4] = t.x; nv[q * 4 + 1] = t.y; nv[q * 4 + 2] = t.z; nv[q * 4 + 3] = t.w;
            }
        }
        int gidv = node_graph[v];
        float gv[4];
        {
            float4 t = *(const float4*)(g + gidv * 4);
            gv[0] = t.x; gv[1] = t.y; gv[2] = t.z; gv[3] = t.w;
        }
        float an[16];
#pragma unroll
        for (int j = 0; j < 16; j++) an[j] = Hn_b[j];
#pragma unroll
        for (int k = 0; k < 16; k++) {
            const float* w = Hn_n + k * 16;
#pragma unroll
            for (int j = 0; j < 16; j++) an[j] = fmaf(nv[k], w[j], an[j]);
        }
#pragma unroll
        for (int k = 0; k < 8; k++) {
            const float* w = Hn_in + k * 16;
#pragma unroll
            for (int j = 0; j < 16; j++) an[j] = fmaf(iv[k], w[j], an[j]);
        }
#pragma unroll
        for (int k = 0; k < 4; k++) {
            const float* w = Hn_g + k * 16;
#pragma unroll
            for (int j = 0; j < 16; j++) an[j] = fmaf(gv[k], w[j], an[j]);
        }
#pragma unroll
        for (int j = 0; j < 16; j++) an[j] = relu_(an[j]);
        {
            float4* pn = (float4*)(nout + (size_t)v * 16);
            pn[0] = make_float4(an[0], an[1], an[2], an[3]);
            pn[1] = make_float4(an[4], an[5], an[6], an[7]);
            pn[2] = make_float4(an[8], an[9], an[10], an[11]);
            pn[3] = make_float4(an[12], an[13], an[14], an[15]);
        }
        if constexpr (MODE == 2) {
            float ro = Rn_b[0];
#pragma unroll
            for (int k = 0; k < 16; k++) ro = fmaf(an[k], Rn[k], ro);
            out[v] = sigmoid_(ro);
        }
    }
    __syncthreads();
    float* sp = slab_e + (size_t)blockIdx.x * (NG * 8);
    for (int i = threadIdx.x; i < NG * 8; i += 256) sp[i] = bins[i];
}

// ---------------- reduce slabs -> gsum_e ----------------
__global__ __launch_bounds__(256) void k_gred_e(const float* __restrict__ slab, float* __restrict__ gsum_e)
{
    int tid = blockIdx.x * 256 + threadIdx.x;  // [0, 2048)
    float s = 0.f;
    for (int b = 0; b < NSLAB; b++) s += slab[(size_t)b * (NG * 8) + tid];
    gsum_e[tid] = s;
}

// ---------------- hop: global update (+ final globals readout) ----------------
__global__ void k_g_hop(
    float* __restrict__ g, const float* __restrict__ gsum_e, const float* __restrict__ gsum_n,
    const int* __restrict__ ecnt, const int* __restrict__ goff,
    const float* __restrict__ Hg_e, const float* __restrict__ Hg_n,
    const float* __restrict__ Hg_g, const float* __restrict__ Hg_b,
    int final_flag, const float* __restrict__ Rg, const float* __restrict__ Rg_b,
    float* __restrict__ out)
{
    int gi = threadIdx.x;
    float ce = 1.f / fmaxf((float)ecnt[gi], 1.f);
    float cn = 1.f / fmaxf((float)(goff[gi + 1] - goff[gi]), 1.f);
    float em[8], nm[16], gold[4];
#pragma unroll
    for (int k = 0; k < 8; k++) em[k] = gsum_e[gi * 8 + k] * ce;
#pragma unroll
    for (int k = 0; k < 16; k++) nm[k] = gsum_n[gi * 16 + k] * cn;
    {
        float4 t = *(const float4*)(g + gi * 4);
        gold[0] = t.x; gold[1] = t.y; gold[2] = t.z; gold[3] = t.w;
    }
    float acc[4];
#pragma unroll
    for (int j = 0; j < 4; j++) acc[j] = Hg_b[j];
#pragma unroll
    for (int k = 0; k < 8; k++) {
        const float* w = Hg_e + k * 4;
#pragma unroll
        for (int j = 0; j < 4; j++) acc[j] = fmaf(em[k], w[j], acc[j]);
    }
#pragma unroll
    for (int k = 0; k < 16; k++) {
        const float* w = Hg_n + k * 4;
#pragma unroll
        for (int j = 0; j < 4; j++) acc[j] = fmaf(nm[k], w[j], acc[j]);
    }
#pragma unroll
    for (int k = 0; k < 4; k++) {
        const float* w = Hg_g + k * 4;
#pragma unroll
        for (int j = 0; j < 4; j++) acc[j] = fmaf(gold[k], w[j], acc[j]);
    }
#pragma unroll
    for (int j = 0; j < 4; j++) acc[j] = relu_(acc[j]);
    *(float4*)(g + gi * 4) = make_float4(acc[0], acc[1], acc[2], acc[3]);
    if (final_flag) {
        float ro = Rg_b[0];
#pragma unroll
        for (int k = 0; k < 4; k++) ro = fmaf(acc[k], Rg[k], ro);
        out[NNODES + gi] = sigmoid_(ro);
    }
}

extern "C" void kernel_launch(void* const* d_in, const int* in_sizes, int n_in,
                              void* d_out, int out_size, void* d_ws, size_t ws_size,
                              hipStream_t stream) {
    const float* nodes      = (const float*)d_in[0];
    const float* edges      = (const float*)d_in[1];
    const int*   senders    = (const int*)d_in[2];
    const int*   receivers  = (const int*)d_in[3];
    const int*   node_graph = (const int*)d_in[4];
    const float* We1 = (const float*)d_in[5];
    const float* be1 = (const float*)d_in[6];
    const float* Wn1 = (const float*)d_in[7];
    const float* bn1 = (const float*)d_in[8];
    const float* We2 = (const float*)d_in[9];
    const float* be2 = (const float*)d_in[10];
    const float* Wn2 = (const float*)d_in[11];
    const float* bn2 = (const float*)d_in[12];
    const float* Wg2 = (const float*)d_in[13];
    const float* bg2 = (const float*)d_in[14];
    const float* He_e = (const float*)d_in[15];
    const float* He_s = (const float*)d_in[16];
    const float* He_g = (const float*)d_in[17];
    const float* He_b = (const float*)d_in[18];
    const float* Hn_n = (const float*)d_in[19];
    const float* Hn_in = (const float*)d_in[20];
    const float* Hn_g = (const float*)d_in[21];
    const float* Hn_b = (const float*)d_in[22];
    const float* Hg_e = (const float*)d_in[23];
    const float* Hg_n = (const float*)d_in[24];
    const float* Hg_g = (const float*)d_in[25];
    const float* Hg_b = (const float*)d_in[26];
    const float* Rn   = (const float*)d_in[27];
    const float* Rn_b = (const float*)d_in[28];
    const float* Rg   = (const float*)d_in[29];
    const float* Rg_b = (const float*)d_in[30];
    float* out = (float*)d_out;

    // ---- workspace layout ----
    char* p = (char*)d_ws;
    float* e      = (float*)p;  p += (size_t)NEDGES * 8 * 4;       // 102.4 MB
    int2*  pairs  = (int2*)p;   p += (size_t)NEDGES * 8;           // 25.6 MB
    float* nbufA  = (float*)p;  p += (size_t)NNODES * 16 * 4;      // 12.8 MB
    float* nbufB  = (float*)p;  p += (size_t)NNODES * 16 * 4;      // 12.8 MB
    float* slab   = (float*)p;  p += (size_t)NSLAB * NG * 8 * 4;   // 4 MB
    int*   deg    = (int*)p;    p += (size_t)NNODES * 4;           // zero region start
    int*   ecnt   = (int*)p;    p += (size_t)NG * 4;               // zero region end
    int*   off    = (int*)p;    p += (size_t)(NNODES + 4) * 4;
    int*   cursor = (int*)p;    p += (size_t)NNODES * 4;
    int*   goff   = (int*)p;    p += (size_t)(NG + 4) * 4;
    int*   bsum   = (int*)p;    p += (size_t)NB1 * 4 + 8;
    int*   bpre   = (int*)p;    p += (size_t)NB1 * 4 + 8;
    float* gsum_n = (float*)p;  p += (size_t)NG * 16 * 4;
    float* gsum_e = (float*)p;  p += (size_t)NG * 8 * 4;
    float* g      = (float*)p;  p += (size_t)NG * 4 * 4;

    hipMemsetAsync(deg, 0, ((size_t)NNODES + NG) * 4, stream);

    // ---- build receiver-sorted CSR permutation (indices only) ----
    k_deg<<<1024, 256, 0, stream>>>(receivers, deg);
    k_scan1<<<NB1, 256, 0, stream>>>(deg, bsum);
    k_scan2<<<1, 64, 0, stream>>>(bsum, bpre);
    k_scan3<<<NB1, 256, 0, stream>>>(deg, bpre, off, cursor);
    k_perm<<<1024, 256, 0, stream>>>(receivers, senders, node_graph, cursor, pairs, ecnt);
    k_goff<<<(NNODES + 255) / 256, 256, 0, stream>>>(node_graph, goff);

    // ---- encoders ----
    k_node_enc<<<(NNODES + 255) / 256, 256, 0, stream>>>(nodes, Wn1, bn1, Wn2, bn2, nbufA);
    k_gsum_nodes<<<NG, 256, 0, stream>>>(nbufA, goff, gsum_n);
    k_g_enc<<<1, NG, 0, stream>>>(gsum_n, goff, Wg2, bg2, g);

    // ---- hop 1 (fused encoder + edge + node) ----
    k_fused_hop<0><<<NSLAB, 256, 0, stream>>>(edges, pairs, off, node_graph, e, nbufA, nbufB, g,
                                              We1, be1, We2, be2, He_e, He_s, He_g, He_b,
                                              Hn_n, Hn_in, Hn_g, Hn_b, slab, Rn, Rn_b, out);
    k_gsum_nodes<<<NG, 256, 0, stream>>>(nbufB, goff, gsum_n);
    k_gred_e<<<NG * 8 / 256, 256, 0, stream>>>(slab, gsum_e);
    k_g_hop<<<1, NG, 0, stream>>>(g, gsum_e, gsum_n, ecnt, goff, Hg_e, Hg_n, Hg_g, Hg_b,
                                  0, Rg, Rg_b, out);
    // ---- hop 2 ----
    k_fused_hop<1><<<NSLAB, 256, 0, stream>>>(edges, pairs, off, node_graph, e, nbufB, nbufA, g,
                                              We1, be1, We2, be2, He_e, He_s, He_g, He_b,
                                              Hn_n, Hn_in, Hn_g, Hn_b, slab, Rn, Rn_b, out);
    k_gsum_nodes<<<NG, 256, 0, stream>>>(nbufA, goff, gsum_n);
    k_gred_e<<<NG * 8 / 256, 256, 0, stream>>>(slab, gsum_e);
    k_g_hop<<<1, NG, 0, stream>>>(g, gsum_e, gsum_n, ecnt, goff, Hg_e, Hg_n, Hg_g, Hg_b,
                                  0, Rg, Rg_b, out);
    // ---- hop 3 (fused node readout; dead e write skipped) ----
    k_fused_hop<2><<<NSLAB, 256, 0, stream>>>(edges, pairs, off, node_graph, e, nbufA, nbufB, g,
                                              We1, be1, We2, be2, He_e, He_s, He_g, He_b,
                                              Hn_n, Hn_in, Hn_g, Hn_b, slab, Rn, Rn_b, out);
    k_gsum_nodes<<<NG, 256, 0, stream>>>(nbufB, goff, gsum_n);
    k_gred_e<<<NG * 8 / 256, 256, 0, stream>>>(slab, gsum_e);
    k_g_hop<<<1, NG, 0, stream>>>(g, gsum_e, gsum_n, ecnt, goff, Hg_e, Hg_n, Hg_g, Hg_b,
                                  1, Rg, Rg_b, out);
}

// Round 4
// 1148.570 us; speedup vs baseline: 1.1181x; 1.1181x over previous
//
#include <hip/hip_runtime.h>
#include <math.h>

#define NNODES 200000
#define NEDGES 3200000
#define NG     256
#define NB1    98      // ceil(200000/2048)
#define NSLAB  1024

static __device__ __forceinline__ float relu_(float x) { return x > 0.f ? x : 0.f; }
static __device__ __forceinline__ float sigmoid_(float x) { return 1.f / (1.f + expf(-x)); }

// ---------------- node encoder ----------------
__global__ __launch_bounds__(256) void k_node_enc(
    const float* __restrict__ nodes,
    const float* __restrict__ Wn1, const float* __restrict__ bn1,
    const float* __restrict__ Wn2, const float* __restrict__ bn2,
    float* __restrict__ nbuf)
{
    int v = blockIdx.x * 256 + threadIdx.x;
    if (v >= NNODES) return;
    float acc1[32];
#pragma unroll
    for (int j = 0; j < 32; j++) acc1[j] = bn1[j];
    const float4* xp = (const float4*)(nodes + (size_t)v * 128);
#pragma unroll 1
    for (int k4 = 0; k4 < 32; k4++) {
        float4 x = xp[k4];
        const float* w = Wn1 + k4 * 4 * 32;
#pragma unroll
        for (int j = 0; j < 32; j++) acc1[j] = fmaf(x.x, w[j], acc1[j]);
#pragma unroll
        for (int j = 0; j < 32; j++) acc1[j] = fmaf(x.y, w[32 + j], acc1[j]);
#pragma unroll
        for (int j = 0; j < 32; j++) acc1[j] = fmaf(x.z, w[64 + j], acc1[j]);
#pragma unroll
        for (int j = 0; j < 32; j++) acc1[j] = fmaf(x.w, w[96 + j], acc1[j]);
    }
#pragma unroll
    for (int j = 0; j < 32; j++) acc1[j] = relu_(acc1[j]);
    float acc2[16];
#pragma unroll
    for (int j = 0; j < 16; j++) acc2[j] = bn2[j];
#pragma unroll 1
    for (int k = 0; k < 32; k++) {
        const float* w = Wn2 + k * 16;
        float x = acc1[k];
#pragma unroll
        for (int j = 0; j < 16; j++) acc2[j] = fmaf(x, w[j], acc2[j]);
    }
    float4* o4 = (float4*)(nbuf + (size_t)v * 16);
    o4[0] = make_float4(relu_(acc2[0]), relu_(acc2[1]), relu_(acc2[2]), relu_(acc2[3]));
    o4[1] = make_float4(relu_(acc2[4]), relu_(acc2[5]), relu_(acc2[6]), relu_(acc2[7]));
    o4[2] = make_float4(relu_(acc2[8]), relu_(acc2[9]), relu_(acc2[10]), relu_(acc2[11]));
    o4[3] = make_float4(relu_(acc2[12]), relu_(acc2[13]), relu_(acc2[14]), relu_(acc2[15]));
}

// ---------------- degree histogram over receivers ----------------
__global__ __launch_bounds__(256) void k_deg(const int* __restrict__ receivers, int* __restrict__ deg)
{
    for (int i = blockIdx.x * 256 + threadIdx.x; i < NEDGES; i += gridDim.x * 256)
        atomicAdd(&deg[receivers[i]], 1);
}

// ---------------- hierarchical exclusive scan of deg -> off, cursor ----------------
__global__ __launch_bounds__(256) void k_scan1(const int* __restrict__ deg, int* __restrict__ bsum)
{
    __shared__ int ts[256];
    int b = blockIdx.x, t = threadIdx.x;
    int base = b * 2048 + t * 8;
    int s = 0;
#pragma unroll
    for (int u = 0; u < 8; u++) { int idx = base + u; if (idx < NNODES) s += deg[idx]; }
    ts[t] = s; __syncthreads();
    for (int ofs = 128; ofs > 0; ofs >>= 1) {
        if (t < ofs) ts[t] += ts[t + ofs];
        __syncthreads();
    }
    if (t == 0) bsum[b] = ts[0];
}

__global__ void k_scan2(const int* __restrict__ bsum, int* __restrict__ bpre)
{
    if (threadIdx.x == 0) {
        int acc = 0;
        for (int i = 0; i < NB1; i++) { bpre[i] = acc; acc += bsum[i]; }
    }
}

__global__ __launch_bounds__(256) void k_scan3(const int* __restrict__ deg, const int* __restrict__ bpre,
                                               int* __restrict__ off, int* __restrict__ cursor)
{
    __shared__ int ts[256];
    int b = blockIdx.x, t = threadIdx.x;
    int base = b * 2048 + t * 8;
    int loc[8]; int s = 0;
#pragma unroll
    for (int u = 0; u < 8; u++) {
        int idx = base + u;
        int d = (idx < NNODES) ? deg[idx] : 0;
        loc[u] = d; s += d;
    }
    ts[t] = s; __syncthreads();
    for (int ofs = 1; ofs < 256; ofs <<= 1) {
        int v = (t >= ofs) ? ts[t - ofs] : 0;
        __syncthreads();
        ts[t] += v;
        __syncthreads();
    }
    int ex = ((t == 0) ? 0 : ts[t - 1]) + bpre[b];
#pragma unroll
    for (int u = 0; u < 8; u++) {
        int idx = base + u;
        if (idx < NNODES) { off[idx] = ex; cursor[idx] = ex; ex += loc[u]; }
    }
    if (b == 0 && t == 0) off[NNODES] = NEDGES;
}

// ---------------- permutation build: index-only scatter; + ecnt hist ----------------
__global__ __launch_bounds__(256) void k_perm(
    const int* __restrict__ receivers, const int* __restrict__ senders,
    const int* __restrict__ node_graph,
    int* __restrict__ cursor, int* __restrict__ eidx_s, int* __restrict__ senders_s,
    int* __restrict__ ecnt)
{
    __shared__ int hist[NG];
    for (int i = threadIdx.x; i < NG; i += 256) hist[i] = 0;
    __syncthreads();
    for (int i = blockIdx.x * 256 + threadIdx.x; i < NEDGES; i += gridDim.x * 256) {
        int r = receivers[i];
        int s = senders[i];
        int pos = atomicAdd(&cursor[r], 1);
        eidx_s[pos] = i;
        senders_s[pos] = s;
        atomicAdd(&hist[node_graph[s]], 1);
    }
    __syncthreads();
    for (int i = threadIdx.x; i < NG; i += 256)
        if (hist[i]) atomicAdd(&ecnt[i], hist[i]);
}

// ---------------- graph start offsets in (sorted) node array ----------------
__global__ __launch_bounds__(256) void k_goff(const int* __restrict__ ng, int* __restrict__ goff)
{
    int v = blockIdx.x * 256 + threadIdx.x;
    if (v >= NNODES) return;
    int a = ng[v];
    if (v == 0) { for (int g = 0; g <= a; g++) goff[g] = 0; }
    else { int b = ng[v - 1]; for (int g = b + 1; g <= a; g++) goff[g] = v; }
    if (v == NNODES - 1) { for (int g = a + 1; g <= NG; g++) goff[g] = NNODES; }
}

// ---------------- per-graph node sum via contiguous ranges ----------------
__global__ __launch_bounds__(256) void k_gsum_nodes(
    const float* __restrict__ nbuf, const int* __restrict__ goff, float* __restrict__ gsum_n)
{
    __shared__ float red[256 * 16];
    int g = blockIdx.x, t = threadIdx.x;
    int s = goff[g], eN = goff[g + 1];
    float acc[16];
#pragma unroll
    for (int j = 0; j < 16; j++) acc[j] = 0.f;
    for (int v = s + t; v < eN; v += 256) {
        const float4* p = (const float4*)(nbuf + (size_t)v * 16);
#pragma unroll
        for (int q = 0; q < 4; q++) {
            float4 x = p[q];
            acc[q * 4] += x.x; acc[q * 4 + 1] += x.y; acc[q * 4 + 2] += x.z; acc[q * 4 + 3] += x.w;
        }
    }
#pragma unroll
    for (int j = 0; j < 16; j++) red[t * 16 + j] = acc[j];
    __syncthreads();
    for (int ofs = 128; ofs > 0; ofs >>= 1) {
        if (t < ofs) {
#pragma unroll
            for (int j = 0; j < 16; j++) red[t * 16 + j] += red[(t + ofs) * 16 + j];
        }
        __syncthreads();
    }
    if (t < 16) gsum_n[g * 16 + t] = red[t];
}

// ---------------- g encoder ----------------
__global__ void k_g_enc(
    const float* __restrict__ gsum_n, const int* __restrict__ goff,
    const float* __restrict__ Wg2, const float* __restrict__ bg2,
    float* __restrict__ g)
{
    int gi = threadIdx.x;
    float c = 1.f / fmaxf((float)(goff[gi + 1] - goff[gi]), 1.f);
    float nm[16];
#pragma unroll
    for (int k = 0; k < 16; k++) nm[k] = gsum_n[gi * 16 + k] * c;
    float acc[4];
#pragma unroll
    for (int j = 0; j < 4; j++) acc[j] = bg2[j];
#pragma unroll
    for (int k = 0; k < 16; k++) {
        const float* w = Wg2 + k * 4;
#pragma unroll
        for (int j = 0; j < 4; j++) acc[j] = fmaf(nm[k], w[j], acc[j]);
    }
    *(float4*)(g + gi * 4) = make_float4(acc[0], acc[1], acc[2], acc[3]);
}

// ---------------- per-edge streaming pass ----------------
// MODE 0: inline-encode raw edge features (gather via eidx_s), write e
// MODE 1: read e, write e
template <int MODE>
__global__ __launch_bounds__(256) void k_edge_pass(
    const float* __restrict__ edges, const int* __restrict__ eidx_s,
    const int* __restrict__ senders_s, const int* __restrict__ node_graph,
    float* __restrict__ e, const float* __restrict__ nin, const float* __restrict__ g,
    const float* __restrict__ We1, const float* __restrict__ be1,
    const float* __restrict__ We2, const float* __restrict__ be2,
    const float* __restrict__ He_e, const float* __restrict__ He_s,
    const float* __restrict__ He_g, const float* __restrict__ He_b,
    float* __restrict__ slab_e)
{
    __shared__ float gs[NG * 4];
    __shared__ float bins[NG * 8];
    for (int i = threadIdx.x; i < NG * 4; i += 256) gs[i] = g[i];
    for (int i = threadIdx.x; i < NG * 8; i += 256) bins[i] = 0.f;
    __syncthreads();
    for (int i = blockIdx.x * 256 + threadIdx.x; i < NEDGES; i += gridDim.x * 256) {
        int s = senders_s[i];
        float ev[8];
        if constexpr (MODE == 0) {
            int eidx = eidx_s[i];
            float x[16];
            const float4* xp = (const float4*)(edges + (size_t)eidx * 16);
#pragma unroll
            for (int q = 0; q < 4; q++) {
                float4 t = xp[q];
                x[q * 4] = t.x; x[q * 4 + 1] = t.y; x[q * 4 + 2] = t.z; x[q * 4 + 3] = t.w;
            }
            float h1[4];
#pragma unroll
            for (int j = 0; j < 4; j++) h1[j] = be1[j];
#pragma unroll
            for (int k = 0; k < 16; k++) {
                const float* w = We1 + k * 4;
#pragma unroll
                for (int j = 0; j < 4; j++) h1[j] = fmaf(x[k], w[j], h1[j]);
            }
#pragma unroll
            for (int j = 0; j < 4; j++) h1[j] = relu_(h1[j]);
#pragma unroll
            for (int j = 0; j < 8; j++) ev[j] = be2[j];
#pragma unroll
            for (int k = 0; k < 4; k++) {
                const float* w = We2 + k * 8;
#pragma unroll
                for (int j = 0; j < 8; j++) ev[j] = fmaf(h1[k], w[j], ev[j]);
            }
#pragma unroll
            for (int j = 0; j < 8; j++) ev[j] = relu_(ev[j]);
        } else {
            const float4* pe = (const float4*)(e + (size_t)i * 8);
            float4 a = pe[0], b = pe[1];
            ev[0] = a.x; ev[1] = a.y; ev[2] = a.z; ev[3] = a.w;
            ev[4] = b.x; ev[5] = b.y; ev[6] = b.z; ev[7] = b.w;
        }
        float ns[16];
        {
            const float4* pn = (const float4*)(nin + (size_t)s * 16);
#pragma unroll
            for (int q = 0; q < 4; q++) {
                float4 t = pn[q];
                ns[q * 4] = t.x; ns[q * 4 + 1] = t.y; ns[q * 4 + 2] = t.z; ns[q * 4 + 3] = t.w;
            }
        }
        int gid = node_graph[s];
        float gv[4];
        {
            gv[0] = gs[gid * 4]; gv[1] = gs[gid * 4 + 1];
            gv[2] = gs[gid * 4 + 2]; gv[3] = gs[gid * 4 + 3];
        }
        float acc[8];
#pragma unroll
        for (int j = 0; j < 8; j++) acc[j] = He_b[j];
#pragma unroll
        for (int k = 0; k < 8; k++) {
            const float* w = He_e + k * 8;
#pragma unroll
            for (int j = 0; j < 8; j++) acc[j] = fmaf(ev[k], w[j], acc[j]);
        }
#pragma unroll
        for (int k = 0; k < 16; k++) {
            const float* w = He_s + k * 8;
#pragma unroll
            for (int j = 0; j < 8; j++) acc[j] = fmaf(ns[k], w[j], acc[j]);
        }
#pragma unroll
        for (int k = 0; k < 4; k++) {
            const float* w = He_g + k * 8;
#pragma unroll
            for (int j = 0; j < 8; j++) acc[j] = fmaf(gv[k], w[j], acc[j]);
        }
#pragma unroll
        for (int j = 0; j < 8; j++) acc[j] = relu_(acc[j]);
        {
            float4* pe = (float4*)(e + (size_t)i * 8);
            pe[0] = make_float4(acc[0], acc[1], acc[2], acc[3]);
            pe[1] = make_float4(acc[4], acc[5], acc[6], acc[7]);
        }
#pragma unroll
        for (int j = 0; j < 8; j++) atomicAdd(&bins[gid * 8 + j], acc[j]);
    }
    __syncthreads();
    float* sp = slab_e + (size_t)blockIdx.x * (NG * 8);
    for (int i = threadIdx.x; i < NG * 8; i += 256) sp[i] = bins[i];
}

// ---------------- reduce slabs -> gsum_e ----------------
__global__ __launch_bounds__(256) void k_gred_e(const float* __restrict__ slab, float* __restrict__ gsum_e)
{
    int tid = blockIdx.x * 256 + threadIdx.x;  // [0, 2048)
    float s = 0.f;
    for (int b = 0; b < NSLAB; b++) s += slab[(size_t)b * (NG * 8) + tid];
    gsum_e[tid] = s;
}

// ---------------- node update: incoming mean from contiguous segment of sorted e ----------------
template <bool LAST>
__global__ __launch_bounds__(256) void k_node_pass(
    const float* __restrict__ e, const int* __restrict__ off,
    const float* __restrict__ nin, float* __restrict__ nout,
    const float* __restrict__ g, const int* __restrict__ node_graph,
    const float* __restrict__ Hn_n, const float* __restrict__ Hn_in,
    const float* __restrict__ Hn_g, const float* __restrict__ Hn_b,
    const float* __restrict__ Rn, const float* __restrict__ Rn_b,
    float* __restrict__ out)
{
    int v = blockIdx.x * 256 + threadIdx.x;
    if (v >= NNODES) return;
    int o0 = off[v], o1 = off[v + 1];
    float iv[8];
#pragma unroll
    for (int j = 0; j < 8; j++) iv[j] = 0.f;
#pragma unroll 1
    for (int j = o0; j < o1; j++) {
        const float4* p = (const float4*)(e + (size_t)j * 8);
        float4 a = p[0], b = p[1];
        iv[0] += a.x; iv[1] += a.y; iv[2] += a.z; iv[3] += a.w;
        iv[4] += b.x; iv[5] += b.y; iv[6] += b.z; iv[7] += b.w;
    }
    float sc = 1.f / fmaxf((float)(o1 - o0), 1.f);
#pragma unroll
    for (int j = 0; j < 8; j++) iv[j] *= sc;
    float nv[16];
    {
        const float4* p = (const float4*)(nin + (size_t)v * 16);
#pragma unroll
        for (int q = 0; q < 4; q++) {
            float4 t = p[q];
            nv[q * 4] = t.x; nv[q * 4 + 1] = t.y; nv[q * 4 + 2] = t.z; nv[q * 4 + 3] = t.w;
        }
    }
    int gid = node_graph[v];
    float gv[4];
    {
        float4 t = *(const float4*)(g + gid * 4);
        gv[0] = t.x; gv[1] = t.y; gv[2] = t.z; gv[3] = t.w;
    }
    float acc[16];
#pragma unroll
    for (int j = 0; j < 16; j++) acc[j] = Hn_b[j];
#pragma unroll
    for (int k = 0; k < 16; k++) {
        const float* w = Hn_n + k * 16;
#pragma unroll
        for (int j = 0; j < 16; j++) acc[j] = fmaf(nv[k], w[j], acc[j]);
    }
#pragma unroll
    for (int k = 0; k < 8; k++) {
        const float* w = Hn_in + k * 16;
#pragma unroll
        for (int j = 0; j < 16; j++) acc[j] = fmaf(iv[k], w[j], acc[j]);
    }
#pragma unroll
    for (int k = 0; k < 4; k++) {
        const float* w = Hn_g + k * 16;
#pragma unroll
        for (int j = 0; j < 16; j++) acc[j] = fmaf(gv[k], w[j], acc[j]);
    }
#pragma unroll
    for (int j = 0; j < 16; j++) acc[j] = relu_(acc[j]);
    float4* p = (float4*)(nout + (size_t)v * 16);
    p[0] = make_float4(acc[0], acc[1], acc[2], acc[3]);
    p[1] = make_float4(acc[4], acc[5], acc[6], acc[7]);
    p[2] = make_float4(acc[8], acc[9], acc[10], acc[11]);
    p[3] = make_float4(acc[12], acc[13], acc[14], acc[15]);
    if constexpr (LAST) {
        float ro = Rn_b[0];
#pragma unroll
        for (int k = 0; k < 16; k++) ro = fmaf(acc[k], Rn[k], ro);
        out[v] = sigmoid_(ro);
    }
}

// ---------------- hop: global update (+ final globals readout) ----------------
__global__ void k_g_hop(
    float* __restrict__ g, const float* __restrict__ gsum_e, const float* __restrict__ gsum_n,
    const int* __restrict__ ecnt, const int* __restrict__ goff,
    const float* __restrict__ Hg_e, const float* __restrict__ Hg_n,
    const float* __restrict__ Hg_g, const float* __restrict__ Hg_b,
    int final_flag, const float* __restrict__ Rg, const float* __restrict__ Rg_b,
    float* __restrict__ out)
{
    int gi = threadIdx.x;
    float ce = 1.f / fmaxf((float)ecnt[gi], 1.f);
    float cn = 1.f / fmaxf((float)(goff[gi + 1] - goff[gi]), 1.f);
    float em[8], nm[16], gold[4];
#pragma unroll
    for (int k = 0; k < 8; k++) em[k] = gsum_e[gi * 8 + k] * ce;
#pragma unroll
    for (int k = 0; k < 16; k++) nm[k] = gsum_n[gi * 16 + k] * cn;
    {
        float4 t = *(const float4*)(g + gi * 4);
        gold[0] = t.x; gold[1] = t.y; gold[2] = t.z; gold[3] = t.w;
    }
    float acc[4];
#pragma unroll
    for (int j = 0; j < 4; j++) acc[j] = Hg_b[j];
#pragma unroll
    for (int k = 0; k < 8; k++) {
        const float* w = Hg_e + k * 4;
#pragma unroll
        for (int j = 0; j < 4; j++) acc[j] = fmaf(em[k], w[j], acc[j]);
    }
#pragma unroll
    for (int k = 0; k < 16; k++) {
        const float* w = Hg_n + k * 4;
#pragma unroll
        for (int j = 0; j < 4; j++) acc[j] = fmaf(nm[k], w[j], acc[j]);
    }
#pragma unroll
    for (int k = 0; k < 4; k++) {
        const float* w = Hg_g + k * 4;
#pragma unroll
        for (int j = 0; j < 4; j++) acc[j] = fmaf(gold[k], w[j], acc[j]);
    }
#pragma unroll
    for (int j = 0; j < 4; j++) acc[j] = relu_(acc[j]);
    *(float4*)(g + gi * 4) = make_float4(acc[0], acc[1], acc[2], acc[3]);
    if (final_flag) {
        float ro = Rg_b[0];
#pragma unroll
        for (int k = 0; k < 4; k++) ro = fmaf(acc[k], Rg[k], ro);
        out[NNODES + gi] = sigmoid_(ro);
    }
}

extern "C" void kernel_launch(void* const* d_in, const int* in_sizes, int n_in,
                              void* d_out, int out_size, void* d_ws, size_t ws_size,
                              hipStream_t stream) {
    const float* nodes      = (const float*)d_in[0];
    const float* edges      = (const float*)d_in[1];
    const int*   senders    = (const int*)d_in[2];
    const int*   receivers  = (const int*)d_in[3];
    const int*   node_graph = (const int*)d_in[4];
    const float* We1 = (const float*)d_in[5];
    const float* be1 = (const float*)d_in[6];
    const float* Wn1 = (const float*)d_in[7];
    const float* bn1 = (const float*)d_in[8];
    const float* We2 = (const float*)d_in[9];
    const float* be2 = (const float*)d_in[10];
    const float* Wn2 = (const float*)d_in[11];
    const float* bn2 = (const float*)d_in[12];
    const float* Wg2 = (const float*)d_in[13];
    const float* bg2 = (const float*)d_in[14];
    const float* He_e = (const float*)d_in[15];
    const float* He_s = (const float*)d_in[16];
    const float* He_g = (const float*)d_in[17];
    const float* He_b = (const float*)d_in[18];
    const float* Hn_n = (const float*)d_in[19];
    const float* Hn_in = (const float*)d_in[20];
    const float* Hn_g = (const float*)d_in[21];
    const float* Hn_b = (const float*)d_in[22];
    const float* Hg_e = (const float*)d_in[23];
    const float* Hg_n = (const float*)d_in[24];
    const float* Hg_g = (const float*)d_in[25];
    const float* Hg_b = (const float*)d_in[26];
    const float* Rn   = (const float*)d_in[27];
    const float* Rn_b = (const float*)d_in[28];
    const float* Rg   = (const float*)d_in[29];
    const float* Rg_b = (const float*)d_in[30];
    float* out = (float*)d_out;

    // ---- workspace layout ----
    char* p = (char*)d_ws;
    float* e         = (float*)p;  p += (size_t)NEDGES * 8 * 4;       // 102.4 MB
    int*   eidx_s    = (int*)p;    p += (size_t)NEDGES * 4;           // 12.8 MB
    int*   senders_s = (int*)p;    p += (size_t)NEDGES * 4;           // 12.8 MB
    float* nbufA     = (float*)p;  p += (size_t)NNODES * 16 * 4;      // 12.8 MB
    float* nbufB     = (float*)p;  p += (size_t)NNODES * 16 * 4;      // 12.8 MB
    float* slab      = (float*)p;  p += (size_t)NSLAB * NG * 8 * 4;   // 8.4 MB
    int*   deg       = (int*)p;    p += (size_t)NNODES * 4;           // zero region start
    int*   ecnt      = (int*)p;    p += (size_t)NG * 4;               // zero region end
    int*   off       = (int*)p;    p += (size_t)(NNODES + 4) * 4;
    int*   cursor    = (int*)p;    p += (size_t)NNODES * 4;
    int*   goff      = (int*)p;    p += (size_t)(NG + 4) * 4;
    int*   bsum      = (int*)p;    p += (size_t)NB1 * 4 + 8;
    int*   bpre      = (int*)p;    p += (size_t)NB1 * 4 + 8;
    float* gsum_n    = (float*)p;  p += (size_t)NG * 16 * 4;
    float* gsum_e    = (float*)p;  p += (size_t)NG * 8 * 4;
    float* g         = (float*)p;  p += (size_t)NG * 4 * 4;

    hipMemsetAsync(deg, 0, ((size_t)NNODES + NG) * 4, stream);

    // ---- build receiver-sorted CSR permutation (indices only) ----
    k_deg<<<1024, 256, 0, stream>>>(receivers, deg);
    k_scan1<<<NB1, 256, 0, stream>>>(deg, bsum);
    k_scan2<<<1, 64, 0, stream>>>(bsum, bpre);
    k_scan3<<<NB1, 256, 0, stream>>>(deg, bpre, off, cursor);
    k_perm<<<1024, 256, 0, stream>>>(receivers, senders, node_graph, cursor,
                                     eidx_s, senders_s, ecnt);
    k_goff<<<(NNODES + 255) / 256, 256, 0, stream>>>(node_graph, goff);

    // ---- encoders ----
    k_node_enc<<<(NNODES + 255) / 256, 256, 0, stream>>>(nodes, Wn1, bn1, Wn2, bn2, nbufA);
    k_gsum_nodes<<<NG, 256, 0, stream>>>(nbufA, goff, gsum_n);
    k_g_enc<<<1, NG, 0, stream>>>(gsum_n, goff, Wg2, bg2, g);

    // ---- hop 1 (edge pass fuses the edge encoder) ----
    k_edge_pass<0><<<NSLAB, 256, 0, stream>>>(edges, eidx_s, senders_s, node_graph, e, nbufA, g,
                                              We1, be1, We2, be2, He_e, He_s, He_g, He_b, slab);
    k_node_pass<false><<<(NNODES + 255) / 256, 256, 0, stream>>>(e, off, nbufA, nbufB, g, node_graph,
                                                                 Hn_n, Hn_in, Hn_g, Hn_b, Rn, Rn_b, out);
    k_gsum_nodes<<<NG, 256, 0, stream>>>(nbufB, goff, gsum_n);
    k_gred_e<<<NG * 8 / 256, 256, 0, stream>>>(slab, gsum_e);
    k_g_hop<<<1, NG, 0, stream>>>(g, gsum_e, gsum_n, ecnt, goff, Hg_e, Hg_n, Hg_g, Hg_b,
                                  0, Rg, Rg_b, out);
    // ---- hop 2 ----
    k_edge_pass<1><<<NSLAB, 256, 0, stream>>>(edges, eidx_s, senders_s, node_graph, e, nbufB, g,
                                              We1, be1, We2, be2, He_e, He_s, He_g, He_b, slab);
    k_node_pass<false><<<(NNODES + 255) / 256, 256, 0, stream>>>(e, off, nbufB, nbufA, g, node_graph,
                                                                 Hn_n, Hn_in, Hn_g, Hn_b, Rn, Rn_b, out);
    k_gsum_nodes<<<NG, 256, 0, stream>>>(nbufA, goff, gsum_n);
    k_gred_e<<<NG * 8 / 256, 256, 0, stream>>>(slab, gsum_e);
    k_g_hop<<<1, NG, 0, stream>>>(g, gsum_e, gsum_n, ecnt, goff, Hg_e, Hg_n, Hg_g, Hg_b,
                                  0, Rg, Rg_b, out);
    // ---- hop 3 (node pass fuses node readout) ----
    k_edge_pass<1><<<NSLAB, 256, 0, stream>>>(edges, eidx_s, senders_s, node_graph, e, nbufA, g,
                                              We1, be1, We2, be2, He_e, He_s, He_g, He_b, slab);
    k_node_pass<true><<<(NNODES + 255) / 256, 256, 0, stream>>>(e, off, nbufA, nbufB, g, node_graph,
                                                                Hn_n, Hn_in, Hn_g, Hn_b, Rn, Rn_b, out);
    k_gsum_nodes<<<NG, 256, 0, stream>>>(nbufB, goff, gsum_n);
    k_gred_e<<<NG * 8 / 256, 256, 0, stream>>>(slab, gsum_e);
    k_g_hop<<<1, NG, 0, stream>>>(g, gsum_e, gsum_n, ecnt, goff, Hg_e, Hg_n, Hg_g, Hg_b,
                                  1, Rg, Rg_b, out);
}